// Round 3
// baseline (831.278 us; speedup 1.0000x reference)
//
#include <hip/hip_runtime.h>
#include <hip/hip_bf16.h>

// ---- types ----
typedef __bf16 bf16x8 __attribute__((ext_vector_type(8), may_alias));
typedef float f32x4 __attribute__((ext_vector_type(4), may_alias));
typedef unsigned short ushort_a __attribute__((may_alias));

#define MFMA(a, b, c) __builtin_amdgcn_mfma_f32_16x16x32_bf16(a, b, c, 0, 0, 0)

__device__ __forceinline__ unsigned short f2bf(float f) {
  return __builtin_bit_cast(unsigned short, (__bf16)f);
}

// ws element layout (ushort):
//   wfB  [2304][384] @ 0         (884736)
//   wgB  [16][384]   @ 884736    (6144, rows 12..15 zero)
//   waoB [384][384]  @ 890880    (147456)
//   wfoB [384][1536] @ 1038336   (589824)

__global__ __launch_bounds__(256) void prep_weights(
    const float* __restrict__ wf, const float* __restrict__ wg,
    const float* __restrict__ wao, const float* __restrict__ wfo,
    unsigned short* __restrict__ ws) {
  int i = blockIdx.x * 256 + threadIdx.x;
  if (i < 884736) { ws[i] = f2bf(wf[i]); return; }
  int j = i - 884736;
  if (j < 6144) { ws[i] = f2bf(j < 4608 ? wg[j] : 0.0f); return; }
  j -= 6144;
  if (j < 147456) { ws[i] = f2bf(wao[j]); return; }
  j -= 147456;
  if (j < 589824) ws[i] = f2bf(wfo[j]);
}

// LDS layout (bytes), 81920 total  -> 2 blocks/CU:
//   As   [64][384] bf16 row-swz        @ 0       (49152)
//   quad regions (2 x 12288)           @ 49152   (24576)
//       QK [64 rows][128B: Q|K] swz, P overlays; KTb [32][64] @ +8192
//   Stg  [64][64] bf16 row-swz         @ 73728   (8192)
//   F tiles (FF phase) alias quad+Stg: fb = 49152 + (t&1)*16384

__global__ __launch_bounds__(512, 4) void fused_main(
    const float* __restrict__ x,
    const float* __restrict__ bgate,
    const float* __restrict__ srs,
    const float* __restrict__ srb,
    const unsigned short* __restrict__ wsb,
    float* __restrict__ out) {
  const unsigned short* wfB  = wsb;
  const unsigned short* wgB  = wsb + 884736;
  const unsigned short* waoB = wsb + 890880;
  const unsigned short* wfoB = wsb + 1038336;

  __shared__ __align__(16) char smem[81920];
  char* As  = smem;
  char* Stg = smem + 73728;

  const int tid = threadIdx.x;
  const int lane = tid & 63, wave = tid >> 6;
  const int l15 = lane & 15, l4 = lane >> 4;
  const int quad = wave >> 2;            // 0/1: which head of the round
  const int nb = (wave & 3) * 16;        // own 16 attn rows
  const int rh = wave & 1, cg = wave >> 1;  // out split: 2 row-halves x 4 col-groups
  char* PB  = smem + 49152 + quad * 12288;  // QK rows, later P
  char* KTb = PB + 8192;                    // [32 d][64 m]

  // XCD swizzle: consecutive windows (sharing x/out cache lines) on one XCD
  const int g  = blockIdx.x;
  const int wi = (g & 7) * 128 + (g >> 3);
  const int b = wi >> 6, ghi = (wi >> 3) & 7, gwi = wi & 7;
  const int h0 = ghi * 8, w0 = gwi * 8;

  // ---- gather window -> LDS bf16 [64 tok][384 ch], XOR row-swizzled ----
  {
    const float* xb = x + (size_t)b * 1572864 + h0 * 64 + w0;
    for (int it = 0; it < 6; ++it) {
      int idx = it * 512 + tid;           // [0, 3072): (c, p1) pairs
      int c = idx % 384, p1 = idx / 384;
      const float* src = xb + (size_t)c * 4096 + p1 * 64;
      float4 v0 = *(const float4*)src;
      float4 v1 = *(const float4*)(src + 4);
      float f[8] = {v0.x, v0.y, v0.z, v0.w, v1.x, v1.y, v1.z, v1.w};
#pragma unroll
      for (int jj = 0; jj < 8; ++jj) {
        int row = p1 * 8 + jj;            // token
        int byte = (row * 768 + c * 2) ^ ((row & 7) << 4);
        *(ushort_a*)(As + byte) = f2bf(f[jj]);
      }
    }
  }
  const float ss = srs[0], sbi = srb[0];
  __syncthreads();

  auto ldA = [&](int row, int ks) -> bf16x8 {
    int byte = (row * 768 + ks * 64 + l4 * 16) ^ ((row & 7) << 4);
    return *(const bf16x8*)(As + byte);
  };

  // ---- gate GEMM over own 16 rows: G[n][h] ----
  f32x4 gfr = {};
  {
    const unsigned short* wg0 = wgB + (size_t)l15 * 384 + l4 * 8;
#pragma unroll 2
    for (int ks = 0; ks < 12; ++ks) {
      bf16x8 bg = *(const bf16x8*)(wg0 + ks * 32);
      bf16x8 a0 = ldA(nb + l15, ks);
      gfr = MFMA(a0, bg, gfr);
    }
    float gb = (l15 < 12) ? bgate[l15] : 0.0f;
    gfr += gb;
  }

  f32x4 of[2][6] = {};  // rows rh*32+{0..32}, cols cg*96+{0..96}

  // ---- attention: 6 rounds x 2 heads (one head per quad, 16 rows per wave)
#pragma unroll 1
  for (int r = 0; r < 6; ++r) {
    const int h = r * 2 + quad;
    // QKV GEMM for own 16 rows
    f32x4 qf[2] = {}, kf[2] = {};
    const unsigned short* wq = wfB + ((size_t)(h * 32) + l15) * 384 + l4 * 8;
    const unsigned short* wk = wq + (size_t)384 * 384;
#pragma unroll 2
    for (int ks = 0; ks < 12; ++ks) {
      bf16x8 a0 = ldA(nb + l15, ks);
#pragma unroll
      for (int nt = 0; nt < 2; ++nt) {
        bf16x8 bq = *(const bf16x8*)(wq + (size_t)nt * 16 * 384 + ks * 32);
        bf16x8 bk = *(const bf16x8*)(wk + (size_t)nt * 16 * 384 + ks * 32);
        qf[nt] = MFMA(a0, bq, qf[nt]);
        kf[nt] = MFMA(a0, bk, kf[nt]);
      }
    }
    // write QK interleaved row [Q(64B)|K(64B)] + KT
#pragma unroll
    for (int nt = 0; nt < 2; ++nt)
#pragma unroll
      for (int rr = 0; rr < 4; ++rr) {
        int n = nb + l4 * 4 + rr;
        int d = nt * 16 + l15;
        int sw = (n & 7) << 4;
        *(ushort_a*)(PB + ((n * 128 + d * 2) ^ sw)) =
            f2bf(qf[nt][rr] * 0.176776695f);
        unsigned short kvv = f2bf(kf[nt][rr]);
        *(ushort_a*)(PB + ((n * 128 + 64 + d * 2) ^ sw)) = kvv;
        *(ushort_a*)(KTb + ((d * 128 + n * 2) ^ ((d & 7) << 4))) = kvv;
      }
    __syncthreads();  // B1: QK/KT visible to quad
    // scores S[n(own 16)][m(all 64)] (K=32, 1 kstep)
    f32x4 sf[4];
    {
      bf16x8 bkv[4];
#pragma unroll
      for (int ni = 0; ni < 4; ++ni) {
        int m = ni * 16 + l15;
        bkv[ni] = *(const bf16x8*)(PB + ((m * 128 + 64 + l4 * 16) ^ ((m & 7) << 4)));
      }
      int n = nb + l15;
      bf16x8 aq = *(const bf16x8*)(PB + ((n * 128 + l4 * 16) ^ ((n & 7) << 4)));
#pragma unroll
      for (int ni = 0; ni < 4; ++ni) sf[ni] = MFMA(aq, bkv[ni], {});
    }
    __syncthreads();  // B2: scores readers done before P overlays QK
    // softmax over m; write P (overlays QK region, own rows only)
#pragma unroll
    for (int rr = 0; rr < 4; ++rr) {
      float v0 = sf[0][rr], v1 = sf[1][rr], v2 = sf[2][rr], v3 = sf[3][rr];
      float mx = fmaxf(fmaxf(v0, v1), fmaxf(v2, v3));
      mx = fmaxf(mx, __shfl_xor(mx, 1, 64));
      mx = fmaxf(mx, __shfl_xor(mx, 2, 64));
      mx = fmaxf(mx, __shfl_xor(mx, 4, 64));
      mx = fmaxf(mx, __shfl_xor(mx, 8, 64));
      float e0 = __expf(v0 - mx), e1 = __expf(v1 - mx),
            e2 = __expf(v2 - mx), e3 = __expf(v3 - mx);
      float sm = e0 + e1 + e2 + e3;
      sm += __shfl_xor(sm, 1, 64);
      sm += __shfl_xor(sm, 2, 64);
      sm += __shfl_xor(sm, 4, 64);
      sm += __shfl_xor(sm, 8, 64);
      float rs = 1.0f / sm;
      int n = nb + l4 * 4 + rr;
      int base = n * 128, sw = (n & 7) << 4;
      *(ushort_a*)(PB + ((base + l15 * 2) ^ sw))      = f2bf(e0 * rs);
      *(ushort_a*)(PB + ((base + 32 + l15 * 2) ^ sw)) = f2bf(e1 * rs);
      *(ushort_a*)(PB + ((base + 64 + l15 * 2) ^ sw)) = f2bf(e2 * rs);
      *(ushort_a*)(PB + ((base + 96 + l15 * 2) ^ sw)) = f2bf(e3 * rs);
    }
    // PV: X[n(own 16)][d] = P·kv   (P rows are own-wave-written: no barrier)
    f32x4 xo[2] = {};
#pragma unroll
    for (int ks = 0; ks < 2; ++ks) {
      bf16x8 bv[2];
#pragma unroll
      for (int nt = 0; nt < 2; ++nt) {
        int d = nt * 16 + l15;
        bv[nt] = *(const bf16x8*)(KTb + ((d * 128 + ks * 64 + l4 * 16) ^ ((d & 7) << 4)));
      }
      int n = nb + l15;
      bf16x8 ap = *(const bf16x8*)(PB + ((n * 128 + ks * 64 + l4 * 16) ^ ((n & 7) << 4)));
      xo[0] = MFMA(ap, bv[0], xo[0]);
      xo[1] = MFMA(ap, bv[1], xo[1]);
    }
    // gate + write gated x_attn chunk into stage [64 rows][64 cols(2 heads)]
#pragma unroll
    for (int rr = 0; rr < 4; ++rr) {
      float gv = __shfl(gfr[rr], (lane & 48) | h, 64);
      float sg = 1.0f / (1.0f + __expf(-gv));
      int n = nb + l4 * 4 + rr;
      int sw = (n & 7) << 4;
      int c0 = quad * 32 + l15;
      *(ushort_a*)(Stg + ((n * 128 + c0 * 2) ^ sw))        = f2bf(xo[0][rr] * sg);
      *(ushort_a*)(Stg + ((n * 128 + (c0 + 16) * 2) ^ sw)) = f2bf(xo[1][rr] * sg);
    }
    __syncthreads();  // B3: Stg visible
    // attn-out accumulate: of += Stg(64x64) · wao[:, r*64 : r*64+64]^T
    {
      const unsigned short* wao0 =
          waoB + (size_t)(cg * 96 + l15) * 384 + r * 64 + l4 * 8;
#pragma unroll
      for (int ks = 0; ks < 2; ++ks) {
        int kb = ks * 64 + l4 * 16;
        int r0 = rh * 32 + l15, r1 = rh * 32 + 16 + l15;
        bf16x8 a0 = *(const bf16x8*)(Stg + ((r0 * 128 + kb) ^ ((r0 & 7) << 4)));
        bf16x8 a1 = *(const bf16x8*)(Stg + ((r1 * 128 + kb) ^ ((r1 & 7) << 4)));
#pragma unroll
        for (int nt = 0; nt < 6; ++nt) {
          bf16x8 bw = *(const bf16x8*)(wao0 + (size_t)nt * 16 * 384 + ks * 32);
          of[0][nt] = MFMA(a0, bw, of[0][nt]);
          of[1][nt] = MFMA(a1, bw, of[1][nt]);
        }
      }
    }
    // next round's writes are ordered by this round's B3 + next B1
  }

  // ---- FF: 12 tiles of 128 cols; StarReLU; of += F · wfo^T (1 barrier/tile)
#pragma unroll 1
  for (int t = 0; t < 12; ++t) {
    f32x4 ffr[4] = {};
    const unsigned short* wfin =
        wfB + (size_t)(768 + t * 128 + wave * 16 + l15) * 384 + l4 * 8;
#pragma unroll 2
    for (int ks = 0; ks < 12; ++ks) {
      bf16x8 a0 = ldA(l15, ks), a1 = ldA(16 + l15, ks),
             a2 = ldA(32 + l15, ks), a3 = ldA(48 + l15, ks);
      bf16x8 bw = *(const bf16x8*)(wfin + ks * 32);
      ffr[0] = MFMA(a0, bw, ffr[0]);
      ffr[1] = MFMA(a1, bw, ffr[1]);
      ffr[2] = MFMA(a2, bw, ffr[2]);
      ffr[3] = MFMA(a3, bw, ffr[3]);
    }
    char* fb = smem + 49152 + (t & 1) * 16384;  // [64][128] bf16, row-swz
#pragma unroll
    for (int mt = 0; mt < 4; ++mt)
#pragma unroll
      for (int rr = 0; rr < 4; ++rr) {
        float v = fmaxf(ffr[mt][rr], 0.0f);
        v = ss * v * v + sbi;  // StarReLU
        int n = mt * 16 + l4 * 4 + rr;
        int cw = wave * 16 + l15;
        *(ushort_a*)(fb + ((n * 256 + cw * 2) ^ ((n & 7) << 4))) = f2bf(v);
      }
    __syncthreads();  // single barrier per tile: fb[t&1] ready
    const unsigned short* wfo2 =
        wfoB + (size_t)(cg * 96 + l15) * 1536 + t * 128 + l4 * 8;
#pragma unroll
    for (int ks = 0; ks < 4; ++ks) {
      int kb = ks * 64 + l4 * 16;
      int r0 = rh * 32 + l15, r1 = rh * 32 + 16 + l15;
      bf16x8 a0 = *(const bf16x8*)(fb + ((r0 * 256 + kb) ^ ((r0 & 7) << 4)));
      bf16x8 a1 = *(const bf16x8*)(fb + ((r1 * 256 + kb) ^ ((r1 & 7) << 4)));
#pragma unroll
      for (int nt = 0; nt < 6; ++nt) {
        bf16x8 bw = *(const bf16x8*)(wfo2 + (size_t)nt * 16 * 1536 + ks * 32);
        of[0][nt] = MFMA(a0, bw, of[0][nt]);
        of[1][nt] = MFMA(a1, bw, of[1][nt]);
      }
    }
  }

  // ---- epilogue: scatter out (fp32, NCHW), vectorized dwordx4 ----
  float* ob = out + (size_t)b * 1572864 + h0 * 64 + w0;
#pragma unroll
  for (int nt = 0; nt < 6; ++nt) {
    int col = cg * 96 + nt * 16 + l15;
    float* oc = ob + (size_t)col * 4096;
#pragma unroll
    for (int mt = 0; mt < 2; ++mt) {
      int n0 = rh * 32 + mt * 16 + l4 * 4;  // 4 consecutive tokens -> 16B store
      *(f32x4*)(oc + (n0 >> 3) * 64 + (n0 & 7)) = of[mt][nt];
    }
  }
}

extern "C" void kernel_launch(void* const* d_in, const int* in_sizes, int n_in,
                              void* d_out, int out_size, void* d_ws, size_t ws_size,
                              hipStream_t stream) {
  const float* x   = (const float*)d_in[0];
  const float* wf  = (const float*)d_in[1];
  const float* wg  = (const float*)d_in[2];
  const float* bg  = (const float*)d_in[3];
  const float* wao = (const float*)d_in[4];
  const float* wfo = (const float*)d_in[5];
  const float* srs = (const float*)d_in[6];
  const float* srb = (const float*)d_in[7];
  unsigned short* ws = (unsigned short*)d_ws;

  prep_weights<<<6360, 256, 0, stream>>>(wf, wg, wao, wfo, ws);
  fused_main<<<1024, 512, 0, stream>>>(x, bg, srs, srb, ws, (float*)d_out);
}

// Round 4
// 720.782 us; speedup vs baseline: 1.1533x; 1.1533x over previous
//
#include <hip/hip_runtime.h>
#include <hip/hip_bf16.h>

// ---- types ----
typedef __bf16 bf16x8 __attribute__((ext_vector_type(8), may_alias));
typedef float f32x4 __attribute__((ext_vector_type(4), may_alias));
typedef unsigned short ushort_a __attribute__((may_alias));

#define MFMA(a, b, c) __builtin_amdgcn_mfma_f32_16x16x32_bf16(a, b, c, 0, 0, 0)

__device__ __forceinline__ unsigned short f2bf(float f) {
  return __builtin_bit_cast(unsigned short, (__bf16)f);
}

// ws element layout (ushort):
//   wfB  [2304][384] @ 0         (884736)
//   wgB  [16][384]   @ 884736    (6144, rows 12..15 zero)
//   waoB [384][384]  @ 890880    (147456)
//   wfoB [384][1536] @ 1038336   (589824)

__global__ __launch_bounds__(256) void prep_weights(
    const float* __restrict__ wf, const float* __restrict__ wg,
    const float* __restrict__ wao, const float* __restrict__ wfo,
    unsigned short* __restrict__ ws) {
  int i = blockIdx.x * 256 + threadIdx.x;
  if (i < 884736) { ws[i] = f2bf(wf[i]); return; }
  int j = i - 884736;
  if (j < 6144) { ws[i] = f2bf(j < 4608 ? wg[j] : 0.0f); return; }
  j -= 6144;
  if (j < 147456) { ws[i] = f2bf(wao[j]); return; }
  j -= 147456;
  if (j < 589824) ws[i] = f2bf(wfo[j]);
}

// LDS layout (bytes), 81920 total  -> 2 blocks/CU:
//   As   [64][384] bf16 row-swz        @ 0       (49152)
//   quad regions (2 x 12288)           @ 49152   (24576)
//       QK [64 rows][128B: Q|K] swz, P overlays; KTb [32][64] @ +8192
//   Stg  [64][64] bf16 row-swz         @ 73728   (8192)
//   F tiles (FF phase) alias quad+Stg: fb = 49152 + (t&1)*16384

__global__ __launch_bounds__(512, 4) void fused_main(
    const float* __restrict__ x,
    const float* __restrict__ bgate,
    const float* __restrict__ srs,
    const float* __restrict__ srb,
    const unsigned short* __restrict__ wsb,
    float* __restrict__ out) {
  const unsigned short* wfB  = wsb;
  const unsigned short* wgB  = wsb + 884736;
  const unsigned short* waoB = wsb + 890880;
  const unsigned short* wfoB = wsb + 1038336;

  __shared__ __align__(16) char smem[81920];
  char* As  = smem;
  char* Stg = smem + 73728;

  const int tid = threadIdx.x;
  const int lane = tid & 63, wave = tid >> 6;
  const int l15 = lane & 15, l4 = lane >> 4;
  const int quad = wave >> 2;            // 0/1: which head of the round
  const int nb = (wave & 3) * 16;        // own 16 attn rows
  char* PB  = smem + 49152 + quad * 12288;  // QK rows, later P
  char* KTb = PB + 8192;                    // [32 d][64 m]

  // XCD swizzle: consecutive windows (sharing x/out cache lines) on one XCD
  const int g  = blockIdx.x;
  const int wi = (g & 7) * 128 + (g >> 3);
  const int b = wi >> 6, ghi = (wi >> 3) & 7, gwi = wi & 7;
  const int h0 = ghi * 8, w0 = gwi * 8;

  // ---- gather window -> LDS bf16 [64 tok][384 ch], XOR row-swizzled ----
  {
    const float* xb = x + (size_t)b * 1572864 + h0 * 64 + w0;
    for (int it = 0; it < 6; ++it) {
      int idx = it * 512 + tid;           // [0, 3072): (c, p1) pairs
      int c = idx % 384, p1 = idx / 384;
      const float* src = xb + (size_t)c * 4096 + p1 * 64;
      float4 v0 = *(const float4*)src;
      float4 v1 = *(const float4*)(src + 4);
      float f[8] = {v0.x, v0.y, v0.z, v0.w, v1.x, v1.y, v1.z, v1.w};
#pragma unroll
      for (int jj = 0; jj < 8; ++jj) {
        int row = p1 * 8 + jj;            // token
        int byte = (row * 768 + c * 2) ^ ((row & 7) << 4);
        *(ushort_a*)(As + byte) = f2bf(f[jj]);
      }
    }
  }
  const float ss = srs[0], sbi = srb[0];
  __syncthreads();

  auto ldA = [&](int row, int ks) -> bf16x8 {
    int byte = (row * 768 + ks * 64 + l4 * 16) ^ ((row & 7) << 4);
    return *(const bf16x8*)(As + byte);
  };

  // ---- gate GEMM over own 16 rows: G[n][h] ----
  f32x4 gfr = {};
  {
    const unsigned short* wg0 = wgB + (size_t)l15 * 384 + l4 * 8;
#pragma unroll 2
    for (int ks = 0; ks < 12; ++ks) {
      bf16x8 bg = *(const bf16x8*)(wg0 + ks * 32);
      bf16x8 a0 = ldA(nb + l15, ks);
      gfr = MFMA(a0, bg, gfr);
    }
    float gb = (l15 < 12) ? bgate[l15] : 0.0f;
    gfr += gb;
  }

  f32x4 of[4][3] = {};  // all 64 rows, cols wave*48+{0..48}

  // ---- attention: 6 rounds x 2 heads (one head per quad, 16 rows per wave)
#pragma unroll 1
  for (int r = 0; r < 6; ++r) {
    const int h = r * 2 + quad;
    // QKV GEMM for own 16 rows
    f32x4 qf[2] = {}, kf[2] = {};
    const unsigned short* wq = wfB + ((size_t)(h * 32) + l15) * 384 + l4 * 8;
    const unsigned short* wk = wq + (size_t)384 * 384;
#pragma unroll 2
    for (int ks = 0; ks < 12; ++ks) {
      bf16x8 a0 = ldA(nb + l15, ks);
#pragma unroll
      for (int nt = 0; nt < 2; ++nt) {
        bf16x8 bq = *(const bf16x8*)(wq + (size_t)nt * 16 * 384 + ks * 32);
        bf16x8 bk = *(const bf16x8*)(wk + (size_t)nt * 16 * 384 + ks * 32);
        qf[nt] = MFMA(a0, bq, qf[nt]);
        kf[nt] = MFMA(a0, bk, kf[nt]);
      }
    }
    // write QK interleaved row [Q(64B)|K(64B)] + KT
#pragma unroll
    for (int nt = 0; nt < 2; ++nt)
#pragma unroll
      for (int rr = 0; rr < 4; ++rr) {
        int n = nb + l4 * 4 + rr;
        int d = nt * 16 + l15;
        int sw = (n & 7) << 4;
        *(ushort_a*)(PB + ((n * 128 + d * 2) ^ sw)) =
            f2bf(qf[nt][rr] * 0.176776695f);
        unsigned short kvv = f2bf(kf[nt][rr]);
        *(ushort_a*)(PB + ((n * 128 + 64 + d * 2) ^ sw)) = kvv;
        *(ushort_a*)(KTb + ((d * 128 + n * 2) ^ ((d & 7) << 4))) = kvv;
      }
    __syncthreads();  // B1: QK/KT visible to quad
    // scores S[n(own 16)][m(all 64)] (K=32, 1 kstep)
    f32x4 sf[4];
    {
      bf16x8 bkv[4];
#pragma unroll
      for (int ni = 0; ni < 4; ++ni) {
        int m = ni * 16 + l15;
        bkv[ni] = *(const bf16x8*)(PB + ((m * 128 + 64 + l4 * 16) ^ ((m & 7) << 4)));
      }
      int n = nb + l15;
      bf16x8 aq = *(const bf16x8*)(PB + ((n * 128 + l4 * 16) ^ ((n & 7) << 4)));
#pragma unroll
      for (int ni = 0; ni < 4; ++ni) sf[ni] = MFMA(aq, bkv[ni], {});
    }
    __syncthreads();  // B2: scores readers done before P overlays QK
    // softmax over m; write P (overlays QK region, own rows only)
#pragma unroll
    for (int rr = 0; rr < 4; ++rr) {
      float v0 = sf[0][rr], v1 = sf[1][rr], v2 = sf[2][rr], v3 = sf[3][rr];
      float mx = fmaxf(fmaxf(v0, v1), fmaxf(v2, v3));
      mx = fmaxf(mx, __shfl_xor(mx, 1, 64));
      mx = fmaxf(mx, __shfl_xor(mx, 2, 64));
      mx = fmaxf(mx, __shfl_xor(mx, 4, 64));
      mx = fmaxf(mx, __shfl_xor(mx, 8, 64));
      float e0 = __expf(v0 - mx), e1 = __expf(v1 - mx),
            e2 = __expf(v2 - mx), e3 = __expf(v3 - mx);
      float sm = e0 + e1 + e2 + e3;
      sm += __shfl_xor(sm, 1, 64);
      sm += __shfl_xor(sm, 2, 64);
      sm += __shfl_xor(sm, 4, 64);
      sm += __shfl_xor(sm, 8, 64);
      float rs = 1.0f / sm;
      int n = nb + l4 * 4 + rr;
      int base = n * 128, sw = (n & 7) << 4;
      *(ushort_a*)(PB + ((base + l15 * 2) ^ sw))      = f2bf(e0 * rs);
      *(ushort_a*)(PB + ((base + 32 + l15 * 2) ^ sw)) = f2bf(e1 * rs);
      *(ushort_a*)(PB + ((base + 64 + l15 * 2) ^ sw)) = f2bf(e2 * rs);
      *(ushort_a*)(PB + ((base + 96 + l15 * 2) ^ sw)) = f2bf(e3 * rs);
    }
    // PV: X[n(own 16)][d] = P·kv   (P rows are own-wave-written: no barrier)
    f32x4 xo[2] = {};
#pragma unroll
    for (int ks = 0; ks < 2; ++ks) {
      bf16x8 bv[2];
#pragma unroll
      for (int nt = 0; nt < 2; ++nt) {
        int d = nt * 16 + l15;
        bv[nt] = *(const bf16x8*)(KTb + ((d * 128 + ks * 64 + l4 * 16) ^ ((d & 7) << 4)));
      }
      int n = nb + l15;
      bf16x8 ap = *(const bf16x8*)(PB + ((n * 128 + ks * 64 + l4 * 16) ^ ((n & 7) << 4)));
      xo[0] = MFMA(ap, bv[0], xo[0]);
      xo[1] = MFMA(ap, bv[1], xo[1]);
    }
    // gate + write gated x_attn chunk into stage [64 rows][64 cols(2 heads)]
#pragma unroll
    for (int rr = 0; rr < 4; ++rr) {
      float gv = __shfl(gfr[rr], (lane & 48) | h, 64);
      float sg = 1.0f / (1.0f + __expf(-gv));
      int n = nb + l4 * 4 + rr;
      int sw = (n & 7) << 4;
      int c0 = quad * 32 + l15;
      *(ushort_a*)(Stg + ((n * 128 + c0 * 2) ^ sw))        = f2bf(xo[0][rr] * sg);
      *(ushort_a*)(Stg + ((n * 128 + (c0 + 16) * 2) ^ sw)) = f2bf(xo[1][rr] * sg);
    }
    __syncthreads();  // B3: Stg visible
    // attn-out accumulate: of += Stg(64x64) · wao[:, r*64 : r*64+64]^T
    {
      const unsigned short* wao0 =
          waoB + (size_t)(wave * 48 + l15) * 384 + r * 64 + l4 * 8;
#pragma unroll
      for (int ks = 0; ks < 2; ++ks) {
        int kb = ks * 64 + l4 * 16;
        bf16x8 a0 = *(const bf16x8*)(Stg + ((l15 * 128 + kb) ^ ((l15 & 7) << 4)));
        bf16x8 a1 = *(const bf16x8*)(Stg + (((16 + l15) * 128 + kb) ^ ((l15 & 7) << 4)));
        bf16x8 a2 = *(const bf16x8*)(Stg + (((32 + l15) * 128 + kb) ^ ((l15 & 7) << 4)));
        bf16x8 a3 = *(const bf16x8*)(Stg + (((48 + l15) * 128 + kb) ^ ((l15 & 7) << 4)));
#pragma unroll
        for (int nt = 0; nt < 3; ++nt) {
          bf16x8 bw = *(const bf16x8*)(wao0 + (size_t)nt * 16 * 384 + ks * 32);
          of[0][nt] = MFMA(a0, bw, of[0][nt]);
          of[1][nt] = MFMA(a1, bw, of[1][nt]);
          of[2][nt] = MFMA(a2, bw, of[2][nt]);
          of[3][nt] = MFMA(a3, bw, of[3][nt]);
        }
      }
    }
    // next round's Stg/PB writes ordered by B3 + next round's B1/B2
  }

  // ---- FF: 12 tiles of 128 cols; StarReLU; of += F · wfo^T (1 barrier/tile)
#pragma unroll 1
  for (int t = 0; t < 12; ++t) {
    f32x4 ffr[4] = {};
    const unsigned short* wfin =
        wfB + (size_t)(768 + t * 128 + wave * 16 + l15) * 384 + l4 * 8;
#pragma unroll 2
    for (int ks = 0; ks < 12; ++ks) {
      bf16x8 a0 = ldA(l15, ks), a1 = ldA(16 + l15, ks),
             a2 = ldA(32 + l15, ks), a3 = ldA(48 + l15, ks);
      bf16x8 bw = *(const bf16x8*)(wfin + ks * 32);
      ffr[0] = MFMA(a0, bw, ffr[0]);
      ffr[1] = MFMA(a1, bw, ffr[1]);
      ffr[2] = MFMA(a2, bw, ffr[2]);
      ffr[3] = MFMA(a3, bw, ffr[3]);
    }
    char* fb = smem + 49152 + (t & 1) * 16384;  // [64][128] bf16, row-swz
#pragma unroll
    for (int mt = 0; mt < 4; ++mt)
#pragma unroll
      for (int rr = 0; rr < 4; ++rr) {
        float v = fmaxf(ffr[mt][rr], 0.0f);
        v = ss * v * v + sbi;  // StarReLU
        int n = mt * 16 + l4 * 4 + rr;
        int cw = wave * 16 + l15;
        *(ushort_a*)(fb + ((n * 256 + cw * 2) ^ ((n & 7) << 4))) = f2bf(v);
      }
    __syncthreads();  // single barrier per tile: fb[t&1] ready
    const unsigned short* wfo2 =
        wfoB + (size_t)(wave * 48 + l15) * 1536 + t * 128 + l4 * 8;
#pragma unroll
    for (int ks = 0; ks < 4; ++ks) {
      int kb = ks * 64 + l4 * 16, sz = (l15 & 7) << 4;
      bf16x8 a0 = *(const bf16x8*)(fb + ((l15 * 256 + kb) ^ sz));
      bf16x8 a1 = *(const bf16x8*)(fb + (((16 + l15) * 256 + kb) ^ sz));
      bf16x8 a2 = *(const bf16x8*)(fb + (((32 + l15) * 256 + kb) ^ sz));
      bf16x8 a3 = *(const bf16x8*)(fb + (((48 + l15) * 256 + kb) ^ sz));
#pragma unroll
      for (int nt = 0; nt < 3; ++nt) {
        bf16x8 bw = *(const bf16x8*)(wfo2 + (size_t)nt * 16 * 1536 + ks * 32);
        of[0][nt] = MFMA(a0, bw, of[0][nt]);
        of[1][nt] = MFMA(a1, bw, of[1][nt]);
        of[2][nt] = MFMA(a2, bw, of[2][nt]);
        of[3][nt] = MFMA(a3, bw, of[3][nt]);
      }
    }
  }

  // ---- epilogue: scatter out (fp32, NCHW), vectorized dwordx4 ----
  float* ob = out + (size_t)b * 1572864 + h0 * 64 + w0;
#pragma unroll
  for (int nt = 0; nt < 3; ++nt) {
    int col = wave * 48 + nt * 16 + l15;
    float* oc = ob + (size_t)col * 4096;
#pragma unroll
    for (int mt = 0; mt < 4; ++mt) {
      int n0 = mt * 16 + l4 * 4;  // 4 consecutive tokens -> 16B store
      *(f32x4*)(oc + (n0 >> 3) * 64 + (n0 & 7)) = of[mt][nt];
    }
  }
}

extern "C" void kernel_launch(void* const* d_in, const int* in_sizes, int n_in,
                              void* d_out, int out_size, void* d_ws, size_t ws_size,
                              hipStream_t stream) {
  const float* x   = (const float*)d_in[0];
  const float* wf  = (const float*)d_in[1];
  const float* wg  = (const float*)d_in[2];
  const float* bg  = (const float*)d_in[3];
  const float* wao = (const float*)d_in[4];
  const float* wfo = (const float*)d_in[5];
  const float* srs = (const float*)d_in[6];
  const float* srb = (const float*)d_in[7];
  unsigned short* ws = (unsigned short*)d_ws;

  prep_weights<<<6360, 256, 0, stream>>>(wf, wg, wao, wfo, ws);
  fused_main<<<1024, 512, 0, stream>>>(x, bg, srs, srb, ws, (float*)d_out);
}

// Round 5
// 624.206 us; speedup vs baseline: 1.3317x; 1.1547x over previous
//
#include <hip/hip_runtime.h>
#include <hip/hip_bf16.h>

// ---- types ----
typedef __bf16 bf16x8 __attribute__((ext_vector_type(8), may_alias));
typedef float f32x4 __attribute__((ext_vector_type(4), may_alias));
typedef unsigned short ushort_a __attribute__((may_alias));

#define MFMA(a, b, c) __builtin_amdgcn_mfma_f32_16x16x32_bf16(a, b, c, 0, 0, 0)

__device__ __forceinline__ unsigned short f2bf(float f) {
  return __builtin_bit_cast(unsigned short, (__bf16)f);
}

// ws element layout (ushort):
//   wfB  [2304][384] @ 0         (884736)
//   wgB  [16][384]   @ 884736    (6144, rows 12..15 zero)
//   waoB [384][384]  @ 890880    (147456)
//   wfoB [384][1536] @ 1038336   (589824)

__global__ __launch_bounds__(256) void prep_weights(
    const float* __restrict__ wf, const float* __restrict__ wg,
    const float* __restrict__ wao, const float* __restrict__ wfo,
    unsigned short* __restrict__ ws) {
  int i = blockIdx.x * 256 + threadIdx.x;
  if (i < 884736) { ws[i] = f2bf(wf[i]); return; }
  int j = i - 884736;
  if (j < 6144) { ws[i] = f2bf(j < 4608 ? wg[j] : 0.0f); return; }
  j -= 6144;
  if (j < 147456) { ws[i] = f2bf(wao[j]); return; }
  j -= 147456;
  if (j < 589824) ws[i] = f2bf(wfo[j]);
}

// LDS layout (bytes), 147456 total (1 block/CU, proven size):
//   As   [128][384] bf16 row-swz   @ 0      (98304)  -- 2 windows
//   pair regions (4 x 12288)       @ 98304  (49152)
//       QK/P [64 rows][128B] swz; KTb [32][64] @ +8192
//   Stg  [64][128] bf16 row-swz    @ 98304  (16384)  aliases pairs 0-1 (after B2.5)
//   fb   [128][128] bf16 row-swz   @ 98304  (32768)  FF phase, aliases pair rgns

__global__ __launch_bounds__(512, 2) void fused_main(
    const float* __restrict__ x,
    const float* __restrict__ bgate,
    const float* __restrict__ srs,
    const float* __restrict__ srb,
    const unsigned short* __restrict__ wsb,
    float* __restrict__ out) {
  const unsigned short* wfB  = wsb;
  const unsigned short* wgB  = wsb + 884736;
  const unsigned short* waoB = wsb + 890880;
  const unsigned short* wfoB = wsb + 1038336;

  __shared__ __align__(16) char smem[147456];
  char* As  = smem;
  char* Stg = smem + 98304;
  char* fb  = smem + 98304;

  const int tid = threadIdx.x;
  const int lane = tid & 63, wave = tid >> 6;
  const int l15 = lane & 15, l4 = lane >> 4;
  const int p = wave >> 1;               // pair 0..3 (head-of-round)
  const int s = wave & 1;                // row-half within pair
  char* PB  = smem + 98304 + p * 12288;  // QK rows, later P (per pair)
  char* KTb = PB + 8192;                 // [32 d][64 m]

  // XCD swizzle over 512 blocks; block handles windows 2*wp, 2*wp+1
  const int g  = blockIdx.x;
  const int wp = (g & 7) * 64 + (g >> 3);
  const int b = wp >> 5, rem = wp & 31;
  const int ghi = rem >> 2, gwq = rem & 3;
  const int h0 = ghi * 8, w0 = gwq * 16;  // 16-wide strip = 2 windows

  // ---- gather 2 windows -> As bf16 [128 tok][384 ch], XOR row-swizzled ----
  {
    const float* xb = x + (size_t)b * 1572864 + h0 * 64 + w0;
    for (int it = 0; it < 12; ++it) {
      int idx = it * 512 + tid;           // [0, 6144): (c, pg) pairs
      int c = idx % 384, pg = idx / 384;  // pg = w2*8 + p1
      int w2 = pg >> 3, p1 = pg & 7;
      const float* src = xb + (size_t)c * 4096 + p1 * 64 + w2 * 8;
      float4 v0 = *(const float4*)src;
      float4 v1 = *(const float4*)(src + 4);
      float f[8] = {v0.x, v0.y, v0.z, v0.w, v1.x, v1.y, v1.z, v1.w};
#pragma unroll
      for (int jj = 0; jj < 8; ++jj) {
        int row = w2 * 64 + p1 * 8 + jj;  // token row 0..127
        int byte = (row * 768 + c * 2) ^ ((row & 7) << 4);
        *(ushort_a*)(As + byte) = f2bf(f[jj]);
      }
    }
  }
  const float ss = srs[0], sbi = srb[0];
  __syncthreads();

  auto ldA = [&](int row, int ks) -> bf16x8 {
    int byte = (row * 768 + ks * 64 + l4 * 16) ^ ((row & 7) << 4);
    return *(const bf16x8*)(As + byte);
  };

  // ---- gate GEMM for the 4 m-tiles this wave will gate ----
  // wave 2p+s handles attn rows {W*64 + s*32 + mt*16} for W=0,1; j4 = W*2+mt
  f32x4 gfr[4] = {};
  {
    const unsigned short* wg0 = wgB + (size_t)l15 * 384 + l4 * 8;
#pragma unroll 2
    for (int ks = 0; ks < 12; ++ks) {
      bf16x8 bg = *(const bf16x8*)(wg0 + ks * 32);
#pragma unroll
      for (int j4 = 0; j4 < 4; ++j4) {
        int row = (j4 >> 1) * 64 + s * 32 + (j4 & 1) * 16 + l15;
        bf16x8 a = ldA(row, ks);
        gfr[j4] = MFMA(a, bg, gfr[j4]);
      }
    }
    float gb = (l15 < 12) ? bgate[l15] : 0.0f;
#pragma unroll
    for (int j4 = 0; j4 < 4; ++j4) gfr[j4] += gb;
  }

  f32x4 of[8][3] = {};  // all 128 rows (8 m-tiles), cols wave*48+{0..48}

  // ---- attention: 6 rounds; round r: window W=r/3, heads hr*4+p (hr=r%3) ----
#pragma unroll 1
  for (int r = 0; r < 6; ++r) {
    const int W = r / 3, hr = r - W * 3;
    const int h = hr * 4 + p;
    const int nb = W * 64 + s * 32;       // own 32 A-rows
    // QKV GEMM for own 32 rows (2 m-tiles)
    f32x4 qf[2][2] = {}, kf[2][2] = {};
    const unsigned short* wq = wfB + ((size_t)(h * 32) + l15) * 384 + l4 * 8;
    const unsigned short* wk = wq + (size_t)384 * 384;
#pragma unroll 2
    for (int ks = 0; ks < 12; ++ks) {
      bf16x8 a0 = ldA(nb + l15, ks), a1 = ldA(nb + 16 + l15, ks);
#pragma unroll
      for (int nt = 0; nt < 2; ++nt) {
        bf16x8 bq = *(const bf16x8*)(wq + (size_t)nt * 16 * 384 + ks * 32);
        bf16x8 bk = *(const bf16x8*)(wk + (size_t)nt * 16 * 384 + ks * 32);
        qf[0][nt] = MFMA(a0, bq, qf[0][nt]);
        qf[1][nt] = MFMA(a1, bq, qf[1][nt]);
        kf[0][nt] = MFMA(a0, bk, kf[0][nt]);
        kf[1][nt] = MFMA(a1, bk, kf[1][nt]);
      }
    }
    // write QK interleaved row [Q(64B)|K(64B)] + KT (region-local rows)
#pragma unroll
    for (int mt = 0; mt < 2; ++mt)
#pragma unroll
      for (int nt = 0; nt < 2; ++nt)
#pragma unroll
        for (int rr = 0; rr < 4; ++rr) {
          int nl = s * 32 + mt * 16 + l4 * 4 + rr;  // 0..63 within window
          int d = nt * 16 + l15;
          int sw = (nl & 7) << 4;
          *(ushort_a*)(PB + ((nl * 128 + d * 2) ^ sw)) =
              f2bf(qf[mt][nt][rr] * 0.176776695f);
          unsigned short kvv = f2bf(kf[mt][nt][rr]);
          *(ushort_a*)(PB + ((nl * 128 + 64 + d * 2) ^ sw)) = kvv;
          *(ushort_a*)(KTb + ((d * 128 + nl * 2) ^ ((d & 7) << 4))) = kvv;
        }
    __syncthreads();  // B1: QK/KT visible within pair
    // scores S[n(own 32)][m(all 64)] (K=32, 1 kstep)
    f32x4 sf[2][4];
    {
      bf16x8 bkv[4];
#pragma unroll
      for (int ni = 0; ni < 4; ++ni) {
        int m = ni * 16 + l15;
        bkv[ni] = *(const bf16x8*)(PB + ((m * 128 + 64 + l4 * 16) ^ ((m & 7) << 4)));
      }
#pragma unroll
      for (int mt = 0; mt < 2; ++mt) {
        int n = s * 32 + mt * 16 + l15;
        bf16x8 aq = *(const bf16x8*)(PB + ((n * 128 + l4 * 16) ^ ((n & 7) << 4)));
#pragma unroll
        for (int ni = 0; ni < 4; ++ni) sf[mt][ni] = MFMA(aq, bkv[ni], {});
      }
    }
    __syncthreads();  // B2: score reads done before P overlays QK
    // softmax over m; write P (own rows)
#pragma unroll
    for (int mt = 0; mt < 2; ++mt) {
#pragma unroll
      for (int rr = 0; rr < 4; ++rr) {
        float v0 = sf[mt][0][rr], v1 = sf[mt][1][rr],
              v2 = sf[mt][2][rr], v3 = sf[mt][3][rr];
        float mx = fmaxf(fmaxf(v0, v1), fmaxf(v2, v3));
        mx = fmaxf(mx, __shfl_xor(mx, 1, 64));
        mx = fmaxf(mx, __shfl_xor(mx, 2, 64));
        mx = fmaxf(mx, __shfl_xor(mx, 4, 64));
        mx = fmaxf(mx, __shfl_xor(mx, 8, 64));
        float e0 = __expf(v0 - mx), e1 = __expf(v1 - mx),
              e2 = __expf(v2 - mx), e3 = __expf(v3 - mx);
        float sm = e0 + e1 + e2 + e3;
        sm += __shfl_xor(sm, 1, 64);
        sm += __shfl_xor(sm, 2, 64);
        sm += __shfl_xor(sm, 4, 64);
        sm += __shfl_xor(sm, 8, 64);
        float rs = 1.0f / sm;
        int nl = s * 32 + mt * 16 + l4 * 4 + rr;
        int base = nl * 128, sw = (nl & 7) << 4;
        *(ushort_a*)(PB + ((base + l15 * 2) ^ sw))      = f2bf(e0 * rs);
        *(ushort_a*)(PB + ((base + 32 + l15 * 2) ^ sw)) = f2bf(e1 * rs);
        *(ushort_a*)(PB + ((base + 64 + l15 * 2) ^ sw)) = f2bf(e2 * rs);
        *(ushort_a*)(PB + ((base + 96 + l15 * 2) ^ sw)) = f2bf(e3 * rs);
      }
    }
    // PV: X[n(own 32)][d] = P·kv  (own P rows, shared KTb)
    f32x4 xo[2][2] = {};
#pragma unroll
    for (int ks = 0; ks < 2; ++ks) {
      bf16x8 bv[2];
#pragma unroll
      for (int nt = 0; nt < 2; ++nt) {
        int d = nt * 16 + l15;
        bv[nt] = *(const bf16x8*)(KTb + ((d * 128 + ks * 64 + l4 * 16) ^ ((d & 7) << 4)));
      }
#pragma unroll
      for (int mt = 0; mt < 2; ++mt) {
        int n = s * 32 + mt * 16 + l15;
        bf16x8 ap = *(const bf16x8*)(PB + ((n * 128 + ks * 64 + l4 * 16) ^ ((n & 7) << 4)));
        xo[mt][0] = MFMA(ap, bv[0], xo[mt][0]);
        xo[mt][1] = MFMA(ap, bv[1], xo[mt][1]);
      }
    }
    __syncthreads();  // B2.5: all PV reads done; Stg may clobber pair 0-1 rgns
    // gate + write gated x_attn chunk into Stg [64 rows(W)][128 cols(4 heads)]
#pragma unroll
    for (int mt = 0; mt < 2; ++mt) {
#pragma unroll
      for (int rr = 0; rr < 4; ++rr) {
        float gv = __shfl(gfr[W * 2 + mt][rr], (lane & 48) | h, 64);
        float sg = 1.0f / (1.0f + __expf(-gv));
        int nl = s * 32 + mt * 16 + l4 * 4 + rr;
        int sw = (nl & 7) << 4;
        int c0 = p * 32 + l15;
        *(ushort_a*)(Stg + ((nl * 256 + c0 * 2) ^ sw))        = f2bf(xo[mt][0][rr] * sg);
        *(ushort_a*)(Stg + ((nl * 256 + (c0 + 16) * 2) ^ sw)) = f2bf(xo[mt][1][rr] * sg);
      }
    }
    __syncthreads();  // B3: Stg visible
    // attn-out accumulate: of[W*4+mt] += Stg(64x128) · wao[:, hr*128:+128]^T
    {
      const unsigned short* wao0 =
          waoB + (size_t)(wave * 48 + l15) * 384 + hr * 128 + l4 * 8;
#pragma unroll
      for (int ks = 0; ks < 4; ++ks) {
        int kb = ks * 64 + l4 * 16, sz = (l15 & 7) << 4;
        bf16x8 a0 = *(const bf16x8*)(Stg + ((l15 * 256 + kb) ^ sz));
        bf16x8 a1 = *(const bf16x8*)(Stg + (((16 + l15) * 256 + kb) ^ sz));
        bf16x8 a2 = *(const bf16x8*)(Stg + (((32 + l15) * 256 + kb) ^ sz));
        bf16x8 a3 = *(const bf16x8*)(Stg + (((48 + l15) * 256 + kb) ^ sz));
#pragma unroll
        for (int nt = 0; nt < 3; ++nt) {
          bf16x8 bw = *(const bf16x8*)(wao0 + (size_t)nt * 16 * 384 + ks * 32);
          of[W * 4 + 0][nt] = MFMA(a0, bw, of[W * 4 + 0][nt]);
          of[W * 4 + 1][nt] = MFMA(a1, bw, of[W * 4 + 1][nt]);
          of[W * 4 + 2][nt] = MFMA(a2, bw, of[W * 4 + 2][nt]);
          of[W * 4 + 3][nt] = MFMA(a3, bw, of[W * 4 + 3][nt]);
        }
      }
    }
    __syncthreads();  // B4: Stg reads done; next round may rewrite pair rgns
  }

  // ---- FF: 12 tiles of 128 cols; StarReLU; of += F · wfo^T ----
#pragma unroll 1
  for (int t = 0; t < 12; ++t) {
    f32x4 ffr[8] = {};
    const unsigned short* wfin =
        wfB + (size_t)(768 + t * 128 + wave * 16 + l15) * 384 + l4 * 8;
#pragma unroll 2
    for (int ks = 0; ks < 12; ++ks) {
      bf16x8 bw = *(const bf16x8*)(wfin + ks * 32);
#pragma unroll
      for (int mt = 0; mt < 8; ++mt) {
        bf16x8 a = ldA(mt * 16 + l15, ks);
        ffr[mt] = MFMA(a, bw, ffr[mt]);
      }
    }
    // StarReLU -> fb [128][128] bf16 (aliases pair rgns; safe after B4/Bc)
#pragma unroll
    for (int mt = 0; mt < 8; ++mt)
#pragma unroll
      for (int rr = 0; rr < 4; ++rr) {
        float v = fmaxf(ffr[mt][rr], 0.0f);
        v = ss * v * v + sbi;  // StarReLU
        int n = mt * 16 + l4 * 4 + rr;
        int cw = wave * 16 + l15;
        *(ushort_a*)(fb + ((n * 256 + cw * 2) ^ ((n & 7) << 4))) = f2bf(v);
      }
    __syncthreads();  // Bw: fb ready
    const unsigned short* wfo2 =
        wfoB + (size_t)(wave * 48 + l15) * 1536 + t * 128 + l4 * 8;
#pragma unroll
    for (int ks = 0; ks < 4; ++ks) {
      int kb = ks * 64 + l4 * 16, sz = (l15 & 7) << 4;
#pragma unroll
      for (int nt = 0; nt < 3; ++nt) {
        bf16x8 bw = *(const bf16x8*)(wfo2 + (size_t)nt * 16 * 1536 + ks * 32);
#pragma unroll
        for (int mt = 0; mt < 8; ++mt) {
          bf16x8 a = *(const bf16x8*)(fb + (((mt * 16 + l15) * 256 + kb) ^ sz));
          of[mt][nt] = MFMA(a, bw, of[mt][nt]);
        }
      }
    }
    __syncthreads();  // Bc: fb reads done before next tile overwrites
  }

  // ---- epilogue: scatter out (fp32, NCHW), vectorized dwordx4 ----
  float* ob = out + (size_t)b * 1572864 + h0 * 64 + w0;
#pragma unroll
  for (int nt = 0; nt < 3; ++nt) {
    int col = wave * 48 + nt * 16 + l15;
    float* oc = ob + (size_t)col * 4096;
#pragma unroll
    for (int mt = 0; mt < 8; ++mt) {
      int w2 = mt >> 2;
      int n0 = (mt & 3) * 16 + l4 * 4;  // token within window
      *(f32x4*)(oc + (n0 >> 3) * 64 + (n0 & 7) + w2 * 8) = of[mt][nt];
    }
  }
}

extern "C" void kernel_launch(void* const* d_in, const int* in_sizes, int n_in,
                              void* d_out, int out_size, void* d_ws, size_t ws_size,
                              hipStream_t stream) {
  const float* x   = (const float*)d_in[0];
  const float* wf  = (const float*)d_in[1];
  const float* wg  = (const float*)d_in[2];
  const float* bg  = (const float*)d_in[3];
  const float* wao = (const float*)d_in[4];
  const float* wfo = (const float*)d_in[5];
  const float* srs = (const float*)d_in[6];
  const float* srb = (const float*)d_in[7];
  unsigned short* ws = (unsigned short*)d_ws;

  prep_weights<<<6360, 256, 0, stream>>>(wf, wg, wao, wfo, ws);
  fused_main<<<512, 512, 0, stream>>>(x, bg, srs, srb, ws, (float*)d_out);
}

// Round 6
// 573.385 us; speedup vs baseline: 1.4498x; 1.0886x over previous
//
#include <hip/hip_runtime.h>
#include <hip/hip_bf16.h>

// ---- types ----
typedef __bf16 bf16x8 __attribute__((ext_vector_type(8), may_alias));
typedef float f32x4 __attribute__((ext_vector_type(4), may_alias));
typedef unsigned short ushort_a __attribute__((may_alias));

#define MFMA(a, b, c) __builtin_amdgcn_mfma_f32_16x16x32_bf16(a, b, c, 0, 0, 0)

__device__ __forceinline__ unsigned short f2bf(float f) {
  return __builtin_bit_cast(unsigned short, (__bf16)f);
}

// ws element layout (ushort):
//   wfB  [2304][384] @ 0         (884736)
//   wgB  [16][384]   @ 884736    (6144, rows 12..15 zero)
//   waoB [384][384]  @ 890880    (147456)
//   wfoB [384][1536] @ 1038336   (589824)

__global__ __launch_bounds__(256) void prep_weights(
    const float* __restrict__ wf, const float* __restrict__ wg,
    const float* __restrict__ wao, const float* __restrict__ wfo,
    unsigned short* __restrict__ ws) {
  int i = blockIdx.x * 256 + threadIdx.x;
  if (i < 884736) { ws[i] = f2bf(wf[i]); return; }
  int j = i - 884736;
  if (j < 6144) { ws[i] = f2bf(j < 4608 ? wg[j] : 0.0f); return; }
  j -= 6144;
  if (j < 147456) { ws[i] = f2bf(wao[j]); return; }
  j -= 147456;
  if (j < 589824) ws[i] = f2bf(wfo[j]);
}

// LDS layout (bytes), 114688 total:
//   As   [64][384] bf16 row-swz        @ 0       (49152)
//   pair regions (4 x 12288)           @ 49152   (49152)
//       QK [64 rows][128B: Q|K] swz, P overlays; KTb [32][64] @ +8192
//   F tiles (FF phase) alias pair rgn: fb{0,1} = 49152 + u*16384
//   Stg  [64][128] bf16 row-swz        @ 98304   (16384)

__global__ __launch_bounds__(512, 2) void fused_main(
    const float* __restrict__ x,
    const float* __restrict__ bgate,
    const float* __restrict__ srs,
    const float* __restrict__ srb,
    const unsigned short* __restrict__ wsb,
    float* __restrict__ out) {
  const unsigned short* wfB  = wsb;
  const unsigned short* wgB  = wsb + 884736;
  const unsigned short* waoB = wsb + 890880;
  const unsigned short* wfoB = wsb + 1038336;

  __shared__ __align__(16) char smem[114688];
  char* As  = smem;
  char* Stg = smem + 98304;

  const int tid = threadIdx.x;
  const int lane = tid & 63, wave = tid >> 6;
  const int l15 = lane & 15, l4 = lane >> 4;
  const int pair = wave >> 1, nb = (wave & 1) * 32;
  char* PB  = smem + 49152 + pair * 12288;  // QK rows, later P
  char* KTb = PB + 8192;                    // [32 d][64 m]

  // XCD swizzle: consecutive windows (sharing x/out cache lines) on one XCD
  const int g  = blockIdx.x;
  const int wi = (g & 7) * 128 + (g >> 3);
  const int b = wi >> 6, ghi = (wi >> 3) & 7, gwi = wi & 7;
  const int h0 = ghi * 8, w0 = gwi * 8;

  // ---- gather window -> LDS bf16 [64 tok][384 ch], XOR row-swizzled ----
  {
    const float* xb = x + (size_t)b * 1572864 + h0 * 64 + w0;
    for (int it = 0; it < 6; ++it) {
      int idx = it * 512 + tid;           // [0, 3072): (c, p1) pairs
      int c = idx % 384, p1 = idx / 384;
      const float* src = xb + (size_t)c * 4096 + p1 * 64;
      float4 v0 = *(const float4*)src;
      float4 v1 = *(const float4*)(src + 4);
      float f[8] = {v0.x, v0.y, v0.z, v0.w, v1.x, v1.y, v1.z, v1.w};
#pragma unroll
      for (int jj = 0; jj < 8; ++jj) {
        int row = p1 * 8 + jj;            // token
        int byte = (row * 768 + c * 2) ^ ((row & 7) << 4);
        *(ushort_a*)(As + byte) = f2bf(f[jj]);
      }
    }
  }
  const float ss = srs[0], sbi = srb[0];
  __syncthreads();

  auto ldA = [&](int row, int ks) -> bf16x8 {
    int byte = (row * 768 + ks * 64 + l4 * 16) ^ ((row & 7) << 4);
    return *(const bf16x8*)(As + byte);
  };

  // ---- gate GEMM over own half rows: G[n][h] ----
  f32x4 gfr[2] = {};
  {
    const unsigned short* wg0 = wgB + (size_t)l15 * 384 + l4 * 8;
#pragma unroll 2
    for (int ks = 0; ks < 12; ++ks) {
      bf16x8 bg = *(const bf16x8*)(wg0 + ks * 32);
      bf16x8 a0 = ldA(nb + l15, ks), a1 = ldA(nb + 16 + l15, ks);
      gfr[0] = MFMA(a0, bg, gfr[0]);
      gfr[1] = MFMA(a1, bg, gfr[1]);
    }
    float gb = (l15 < 12) ? bgate[l15] : 0.0f;
    gfr[0] += gb;
    gfr[1] += gb;
  }

  f32x4 of[4][3] = {};  // 48 out cols per wave, accumulated attn-out + FF-out

  // ---- attention: 3 rounds x 4 heads (one head per pair, half rows per wave)
#pragma unroll 1
  for (int r = 0; r < 3; ++r) {
    const int h = r * 4 + pair;
    // QKV GEMM for own half rows
    f32x4 qf[2][2] = {}, kf[2][2] = {};
    const unsigned short* wq = wfB + ((size_t)(h * 32) + l15) * 384 + l4 * 8;
    const unsigned short* wk = wq + (size_t)384 * 384;
#pragma unroll 2
    for (int ks = 0; ks < 12; ++ks) {
      bf16x8 a0 = ldA(nb + l15, ks), a1 = ldA(nb + 16 + l15, ks);
#pragma unroll
      for (int nt = 0; nt < 2; ++nt) {
        bf16x8 bq = *(const bf16x8*)(wq + (size_t)nt * 16 * 384 + ks * 32);
        bf16x8 bk = *(const bf16x8*)(wk + (size_t)nt * 16 * 384 + ks * 32);
        qf[0][nt] = MFMA(a0, bq, qf[0][nt]);
        qf[1][nt] = MFMA(a1, bq, qf[1][nt]);
        kf[0][nt] = MFMA(a0, bk, kf[0][nt]);
        kf[1][nt] = MFMA(a1, bk, kf[1][nt]);
      }
    }
    // write QK interleaved row [Q(64B)|K(64B)] + KT (own rows / own m-half)
#pragma unroll
    for (int mt = 0; mt < 2; ++mt)
#pragma unroll
      for (int nt = 0; nt < 2; ++nt)
#pragma unroll
        for (int rr = 0; rr < 4; ++rr) {
          int n = nb + mt * 16 + l4 * 4 + rr;
          int d = nt * 16 + l15;
          int sw = (n & 7) << 4;
          *(ushort_a*)(PB + ((n * 128 + d * 2) ^ sw)) =
              f2bf(qf[mt][nt][rr] * 0.176776695f);
          unsigned short kvv = f2bf(kf[mt][nt][rr]);
          *(ushort_a*)(PB + ((n * 128 + 64 + d * 2) ^ sw)) = kvv;
          *(ushort_a*)(KTb + ((d * 128 + n * 2) ^ ((d & 7) << 4))) = kvv;
        }
    __syncthreads();
    // scores S[n(own half)][m(all)] (K=32, 1 kstep)
    f32x4 sf[2][4] = {};
    {
      bf16x8 bkv[4];
#pragma unroll
      for (int ni = 0; ni < 4; ++ni) {
        int m = ni * 16 + l15;
        bkv[ni] = *(const bf16x8*)(PB + ((m * 128 + 64 + l4 * 16) ^ ((m & 7) << 4)));
      }
#pragma unroll
      for (int mt = 0; mt < 2; ++mt) {
        int n = nb + mt * 16 + l15;
        bf16x8 aq = *(const bf16x8*)(PB + ((n * 128 + l4 * 16) ^ ((n & 7) << 4)));
#pragma unroll
        for (int ni = 0; ni < 4; ++ni) sf[mt][ni] = MFMA(aq, bkv[ni], sf[mt][ni]);
      }
    }
    __syncthreads();  // before P overlays QK
    // softmax over m; write P (overlays QK region)
#pragma unroll
    for (int mt = 0; mt < 2; ++mt) {
#pragma unroll
      for (int rr = 0; rr < 4; ++rr) {
        float v0 = sf[mt][0][rr], v1 = sf[mt][1][rr],
              v2 = sf[mt][2][rr], v3 = sf[mt][3][rr];
        float mx = fmaxf(fmaxf(v0, v1), fmaxf(v2, v3));
        mx = fmaxf(mx, __shfl_xor(mx, 1, 64));
        mx = fmaxf(mx, __shfl_xor(mx, 2, 64));
        mx = fmaxf(mx, __shfl_xor(mx, 4, 64));
        mx = fmaxf(mx, __shfl_xor(mx, 8, 64));
        float e0 = __expf(v0 - mx), e1 = __expf(v1 - mx),
              e2 = __expf(v2 - mx), e3 = __expf(v3 - mx);
        float sm = e0 + e1 + e2 + e3;
        sm += __shfl_xor(sm, 1, 64);
        sm += __shfl_xor(sm, 2, 64);
        sm += __shfl_xor(sm, 4, 64);
        sm += __shfl_xor(sm, 8, 64);
        float rs = 1.0f / sm;
        int n = nb + mt * 16 + l4 * 4 + rr;
        int base = n * 128, sw = (n & 7) << 4;
        *(ushort_a*)(PB + ((base + l15 * 2) ^ sw))      = f2bf(e0 * rs);
        *(ushort_a*)(PB + ((base + 32 + l15 * 2) ^ sw)) = f2bf(e1 * rs);
        *(ushort_a*)(PB + ((base + 64 + l15 * 2) ^ sw)) = f2bf(e2 * rs);
        *(ushort_a*)(PB + ((base + 96 + l15 * 2) ^ sw)) = f2bf(e3 * rs);
      }
    }
    // PV: X[n(own half)][d] = P·kv (reads own P rows + shared KTb)
    f32x4 xo[2][2] = {};
#pragma unroll
    for (int ks = 0; ks < 2; ++ks) {
      bf16x8 bv[2];
#pragma unroll
      for (int nt = 0; nt < 2; ++nt) {
        int d = nt * 16 + l15;
        bv[nt] = *(const bf16x8*)(KTb + ((d * 128 + ks * 64 + l4 * 16) ^ ((d & 7) << 4)));
      }
#pragma unroll
      for (int mt = 0; mt < 2; ++mt) {
        int n = nb + mt * 16 + l15;
        bf16x8 ap = *(const bf16x8*)(PB + ((n * 128 + ks * 64 + l4 * 16) ^ ((n & 7) << 4)));
        xo[mt][0] = MFMA(ap, bv[0], xo[mt][0]);
        xo[mt][1] = MFMA(ap, bv[1], xo[mt][1]);
      }
    }
    // gate + write gated x_attn chunk into stage [64][128]
#pragma unroll
    for (int mt = 0; mt < 2; ++mt) {
#pragma unroll
      for (int rr = 0; rr < 4; ++rr) {
        float gv = __shfl(gfr[mt][rr], (lane & 48) | h, 64);
        float sg = 1.0f / (1.0f + __expf(-gv));
        int n = nb + mt * 16 + l4 * 4 + rr;
        int sw = (n & 7) << 4;
        int c0 = pair * 32 + l15;
        *(ushort_a*)(Stg + ((n * 256 + c0 * 2) ^ sw))        = f2bf(xo[mt][0][rr] * sg);
        *(ushort_a*)(Stg + ((n * 256 + (c0 + 16) * 2) ^ sw)) = f2bf(xo[mt][1][rr] * sg);
      }
    }
    __syncthreads();
    // attn-out accumulate: of += Stg(64x128) · wao[:, r*128 : r*128+128]^T
    {
      const unsigned short* wao0 =
          waoB + (size_t)(wave * 48 + l15) * 384 + r * 128 + l4 * 8;
#pragma unroll
      for (int ks = 0; ks < 4; ++ks) {
        int kb = ks * 64 + l4 * 16, sz = (l15 & 7) << 4;
        bf16x8 a0 = *(const bf16x8*)(Stg + ((l15 * 256 + kb) ^ sz));
        bf16x8 a1 = *(const bf16x8*)(Stg + (((16 + l15) * 256 + kb) ^ sz));
        bf16x8 a2 = *(const bf16x8*)(Stg + (((32 + l15) * 256 + kb) ^ sz));
        bf16x8 a3 = *(const bf16x8*)(Stg + (((48 + l15) * 256 + kb) ^ sz));
#pragma unroll
        for (int nt = 0; nt < 3; ++nt) {
          bf16x8 bw = *(const bf16x8*)(wao0 + (size_t)nt * 16 * 384 + ks * 32);
          of[0][nt] = MFMA(a0, bw, of[0][nt]);
          of[1][nt] = MFMA(a1, bw, of[1][nt]);
          of[2][nt] = MFMA(a2, bw, of[2][nt]);
          of[3][nt] = MFMA(a3, bw, of[3][nt]);
        }
      }
    }
    // no barrier needed: next round's first barrier orders region reuse
  }

  // ---- FF: 6 groups of 2 tiles (128 cols each); StarReLU; of += F · wfo^T
  // Pairing doubles A-fragment reuse in produce (each ldA feeds 8 MFMAs).
#pragma unroll 1
  for (int tg = 0; tg < 6; ++tg) {
    f32x4 ffr[4][2] = {};
    const unsigned short* wfin0 =
        wfB + (size_t)(768 + tg * 256 + wave * 16 + l15) * 384 + l4 * 8;
    const unsigned short* wfin1 = wfin0 + (size_t)128 * 384;
#pragma unroll 2
    for (int ks = 0; ks < 12; ++ks) {
      bf16x8 a0 = ldA(l15, ks), a1 = ldA(16 + l15, ks),
             a2 = ldA(32 + l15, ks), a3 = ldA(48 + l15, ks);
      bf16x8 bw0 = *(const bf16x8*)(wfin0 + ks * 32);
      ffr[0][0] = MFMA(a0, bw0, ffr[0][0]);
      ffr[1][0] = MFMA(a1, bw0, ffr[1][0]);
      ffr[2][0] = MFMA(a2, bw0, ffr[2][0]);
      ffr[3][0] = MFMA(a3, bw0, ffr[3][0]);
      bf16x8 bw1 = *(const bf16x8*)(wfin1 + ks * 32);
      ffr[0][1] = MFMA(a0, bw1, ffr[0][1]);
      ffr[1][1] = MFMA(a1, bw1, ffr[1][1]);
      ffr[2][1] = MFMA(a2, bw1, ffr[2][1]);
      ffr[3][1] = MFMA(a3, bw1, ffr[3][1]);
    }
    // StarReLU -> both fb buffers [64][128] bf16, row-swz
#pragma unroll
    for (int u = 0; u < 2; ++u) {
      char* fb = smem + 49152 + u * 16384;
#pragma unroll
      for (int mt = 0; mt < 4; ++mt)
#pragma unroll
        for (int rr = 0; rr < 4; ++rr) {
          float v = fmaxf(ffr[mt][u][rr], 0.0f);
          v = ss * v * v + sbi;  // StarReLU
          int n = mt * 16 + l4 * 4 + rr;
          int cw = wave * 16 + l15;
          *(ushort_a*)(fb + ((n * 256 + cw * 2) ^ ((n & 7) << 4))) = f2bf(v);
        }
    }
    __syncthreads();  // produce done: fb0+fb1 ready
    // consume both tiles
#pragma unroll 1
    for (int u = 0; u < 2; ++u) {
      char* fb = smem + 49152 + u * 16384;
      const unsigned short* wfo2 =
          wfoB + (size_t)(wave * 48 + l15) * 1536 + (tg * 2 + u) * 128 + l4 * 8;
#pragma unroll
      for (int ks = 0; ks < 4; ++ks) {
        int kb = ks * 64 + l4 * 16, sz = (l15 & 7) << 4;
        bf16x8 a0 = *(const bf16x8*)(fb + ((l15 * 256 + kb) ^ sz));
        bf16x8 a1 = *(const bf16x8*)(fb + (((16 + l15) * 256 + kb) ^ sz));
        bf16x8 a2 = *(const bf16x8*)(fb + (((32 + l15) * 256 + kb) ^ sz));
        bf16x8 a3 = *(const bf16x8*)(fb + (((48 + l15) * 256 + kb) ^ sz));
#pragma unroll
        for (int nt = 0; nt < 3; ++nt) {
          bf16x8 bw = *(const bf16x8*)(wfo2 + (size_t)nt * 16 * 1536 + ks * 32);
          of[0][nt] = MFMA(a0, bw, of[0][nt]);
          of[1][nt] = MFMA(a1, bw, of[1][nt]);
          of[2][nt] = MFMA(a2, bw, of[2][nt]);
          of[3][nt] = MFMA(a3, bw, of[3][nt]);
        }
      }
    }
    __syncthreads();  // consume done: next group may overwrite fb0/fb1
  }

  // ---- epilogue: scatter out (fp32, NCHW), vectorized dwordx4 ----
  float* ob = out + (size_t)b * 1572864 + h0 * 64 + w0;
#pragma unroll
  for (int nt = 0; nt < 3; ++nt) {
    int col = wave * 48 + nt * 16 + l15;
    float* oc = ob + (size_t)col * 4096;
#pragma unroll
    for (int mt = 0; mt < 4; ++mt) {
      int n0 = mt * 16 + l4 * 4;  // 4 consecutive tokens -> 16B store
      *(f32x4*)(oc + (n0 >> 3) * 64 + (n0 & 7)) = of[mt][nt];
    }
  }
}

extern "C" void kernel_launch(void* const* d_in, const int* in_sizes, int n_in,
                              void* d_out, int out_size, void* d_ws, size_t ws_size,
                              hipStream_t stream) {
  const float* x   = (const float*)d_in[0];
  const float* wf  = (const float*)d_in[1];
  const float* wg  = (const float*)d_in[2];
  const float* bg  = (const float*)d_in[3];
  const float* wao = (const float*)d_in[4];
  const float* wfo = (const float*)d_in[5];
  const float* srs = (const float*)d_in[6];
  const float* srb = (const float*)d_in[7];
  unsigned short* ws = (unsigned short*)d_ws;

  prep_weights<<<6360, 256, 0, stream>>>(wf, wg, wao, wfo, ws);
  fused_main<<<1024, 512, 0, stream>>>(x, bg, srs, srb, ws, (float*)d_out);
}